// Round 17
// baseline (448.166 us; speedup 1.0000x reference)
//
#include <hip/hip_runtime.h>
#include <hip/hip_fp16.h>
#include <math.h>

#define D 128
#define NBUCK_MAX 128
#define BROWS 1024   // rows per bucket (bshift=10); requires N <= 131072 (col packs in 17 bits)

typedef _Float16 f16x8 __attribute__((ext_vector_type(8)));
typedef __attribute__((ext_vector_type(4))) float f32x4;

static __device__ __forceinline__ unsigned short f2h(float f) {
  __half h = __float2half(f);
  return *reinterpret_cast<unsigned short*>(&h);
}
static __device__ __forceinline__ __half2 u2h(unsigned u) { return *reinterpret_cast<__half2*>(&u); }
static __device__ __forceinline__ unsigned h2u(__half2 h) { return *reinterpret_cast<unsigned*>(&h); }

// ---- radix partition by bucket (row >> bshift), WG-private histograms ----
__global__ __launch_bounds__(256) void wg_hist(const int* __restrict__ rows, int* __restrict__ wghist,
                                               int E, int NW, int per, int bshift) {
  __shared__ int cnt[NBUCK_MAX];
  int tid = threadIdx.x, w = blockIdx.x;
  if (tid < NBUCK_MAX) cnt[tid] = 0;
  __syncthreads();
  int base = w * per;
  int end = base + per; if (end > E) end = E;
  for (int e = base + tid; e < end; e += 256) atomicAdd(&cnt[rows[e] >> bshift], 1);
  __syncthreads();
  if (tid < NBUCK_MAX) wghist[tid * NW + w] = cnt[tid];
}

__global__ __launch_bounds__(512) void scan_wg(const int* __restrict__ wghist, int* __restrict__ wgstart,
                                               int* __restrict__ btot, int NW) {
  int b = blockIdx.x, t = threadIdx.x;
  __shared__ int s[512];
  int v = (t < NW) ? wghist[b * NW + t] : 0;
  s[t] = v;
  __syncthreads();
  for (int d = 1; d < 512; d <<= 1) {
    int x = (t >= d) ? s[t - d] : 0;
    __syncthreads();
    s[t] += x;
    __syncthreads();
  }
  if (t < NW) wgstart[b * NW + t] = s[t] - v;
  if (t == 511) btot[b] = s[511];
}

// inclusive 128-wide prefix of btot into bp[] (LDS); call with >=128 threads, all hitting barriers
static __device__ __forceinline__ void scan_btot_lds(const int* __restrict__ btot, int* bp, int tid) {
  if (tid < NBUCK_MAX) bp[tid] = btot[tid];
  __syncthreads();
  for (int d = 1; d < NBUCK_MAX; d <<= 1) {
    int x = (tid >= d && tid < NBUCK_MAX) ? bp[tid - d] : 0;
    __syncthreads();
    if (tid < NBUCK_MAX) bp[tid] += x;
    __syncthreads();
  }
}

__global__ __launch_bounds__(256) void partition_kernel(const int* __restrict__ rows, const int* __restrict__ cols,
                                                        const float* __restrict__ vals, const int* __restrict__ wgstart,
                                                        const int* __restrict__ btot,
                                                        uint2* __restrict__ gbin, int E, int NW, int per, int bshift) {
  __shared__ int bp[NBUCK_MAX];
  __shared__ int cur[NBUCK_MAX];
  int tid = threadIdx.x, w = blockIdx.x;
  scan_btot_lds(btot, bp, tid);
  if (tid < NBUCK_MAX) cur[tid] = (tid ? bp[tid - 1] : 0) + wgstart[tid * NW + w];
  __syncthreads();
  unsigned rmask = (1u << bshift) - 1u;
  int base = w * per;
  int end = base + per; if (end > E) end = E;
  for (int e = base + tid; e < end; e += 256) {
    unsigned r = (unsigned)rows[e];
    int b = r >> bshift;
    int pos = atomicAdd(&cur[b], 1);
    gbin[pos] = make_uint2(((r & rmask) << 17) | (unsigned)cols[e], __float_as_uint(vals[e]));
  }
}

// per-bucket: LDS row-histogram + scan -> row offsets; scatter into final CSR ep
// ep entry: .x = gather-row byte offset (col*256), .y = val as packed half2 (h | h<<16)
__global__ __launch_bounds__(256) void debin2(const uint2* __restrict__ gbin, const int* __restrict__ btot,
                                              int* __restrict__ offsets, uint2* __restrict__ ep,
                                              int N, int E, int bshift, int NBUCK) {
  __shared__ int bp[NBUCK_MAX];
  __shared__ int cnt[BROWS];
  __shared__ int sblk[256];
  int b = blockIdx.x, t = threadIdx.x;
  scan_btot_lds(btot, bp, t);
  int s0 = (b ? bp[b - 1] : 0), e0 = bp[b];
  int r0 = b << bshift;
  int r1 = r0 + BROWS; if (r1 > N) r1 = N;
  int nr = r1 - r0;
#pragma unroll
  for (int q = 0; q < 4; ++q) cnt[t * 4 + q] = 0;
  __syncthreads();
  for (int i = s0 + t; i < e0; i += 256) atomicAdd(&cnt[gbin[i].x >> 17], 1);
  __syncthreads();
  int c[4]; int tsum = 0;
#pragma unroll
  for (int q = 0; q < 4; ++q) { c[q] = cnt[4 * t + q]; tsum += c[q]; }
  sblk[t] = tsum;
  __syncthreads();
  for (int d = 1; d < 256; d <<= 1) {
    int x = (t >= d) ? sblk[t - d] : 0;
    __syncthreads();
    sblk[t] += x;
    __syncthreads();
  }
  int run = s0 + sblk[t] - tsum;
#pragma unroll
  for (int q = 0; q < 4; ++q) {
    int j = 4 * t + q;
    if (j < nr) offsets[r0 + j] = run;
    cnt[j] = run;   // reuse as absolute cursor
    run += c[q];
  }
  __syncthreads();
  for (int i = s0 + t; i < e0; i += 256) {
    uint2 en = gbin[i];
    int lr = (int)(en.x >> 17);
    int pos = atomicAdd(&cnt[lr], 1);
    unsigned short h = f2h(__uint_as_float(en.y));
    ep[pos] = make_uint2((en.x & 0x1FFFFu) << 8, ((unsigned)h << 16) | (unsigned)h);
  }
  if (b == NBUCK - 1 && t == 0) offsets[N] = E;
}

// ---------------- fp32 -> fp16 converter (emb and W in one launch) ----------------
__global__ __launch_bounds__(256) void conv_f16(const float* __restrict__ a, unsigned short* __restrict__ oa,
                                                const float* __restrict__ bsrc, unsigned short* __restrict__ ob,
                                                int n8a, int n8tot) {
  int t = blockIdx.x * 256 + threadIdx.x;
  if (t >= n8tot) return;
  const float* src = (t < n8a) ? a : bsrc;
  unsigned short* dst = (t < n8a) ? oa : ob;
  int idx = (t < n8a) ? t : t - n8a;
  size_t base = (size_t)idx * 8;
  float4 x = *(const float4*)&src[base];
  float4 y = *(const float4*)&src[base + 4];
  ushort4 o0, o1;
  o0.x = f2h(x.x); o0.y = f2h(x.y); o0.z = f2h(x.z); o0.w = f2h(x.w);
  o1.x = f2h(y.x); o1.y = f2h(y.y); o1.z = f2h(y.z); o1.w = f2h(y.w);
  *(ushort4*)&dst[base] = o0;
  *(ushort4*)&dst[base + 4] = o1;
}

// ---------------- fused layer v4: software-pipelined halves ----------------
// (A·(x·Wᵀ)) == ((A·x)·Wᵀ). Block = 1024 threads = 16 waves, 128 rows in two 64-row halves.
// Schedule: GATHER(0); B; COMPUTE(0)+GATHER(1); B; STORE(0)+COMPUTE(1); B; STORE(1).
// Every MFMA phase co-issues with gather/store memory work -> memory pipe stays fed.
// LAST=0: fp16 Xout + row norm.  LAST=1: fused combine (fp16 x0 term) -> fp32 out.
template <int LAST>
__global__ __launch_bounds__(1024, 8) void spgemm_kernel(
    const char* __restrict__ Xg, const unsigned short* __restrict__ wb,
    const int* __restrict__ offs, const uint2* __restrict__ ep,
    unsigned short* __restrict__ Xout, float* __restrict__ nrmL,
    const unsigned short* __restrict__ x0b, const unsigned short* __restrict__ x1b,
    const unsigned short* __restrict__ x2b, const float* __restrict__ nrm01,
    float* __restrict__ outp, int N, float scl) {
  __shared__ uint4 zt[128][16];       // z rows (f16), chunk c at c ^ (grow&7)
  __shared__ uint2 ytr[2][64][32];    // y rows per half, uint2-chunk c at c ^ ((row&7)<<1)
  __shared__ float nrmp[2][64][9];    // per-(half,row,mt) partial ||y||^2
  int tid = threadIdx.x;
  int wave = tid >> 6, lane = tid & 63;
  int g = lane >> 4, l = lane & 15;
  int lr = l, lk = g;
  int r0g = blockIdx.x * 128;
  int mt = wave & 7, rgb = wave >> 3;

  // W fragment for this wave's col-tile, loaded once
  const unsigned short* wbase = wb + (size_t)(mt * 16 + lr) * D + lk * 8;
  f16x8 wf[4];
#pragma unroll
  for (int s = 0; s < 4; ++s) wf[s] = *(const f16x8*)(wbase + 32 * s);

  // ---- GATHER(h): wave gathers 4 rows of half h ----
  auto GATHER = [&](int h) {
    for (int j = 0; j < 4; ++j) {
      int grow = h * 64 + wave * 4 + j;
      int r = r0g + grow;
      unsigned acc[4] = {0u, 0u, 0u, 0u};
      if (r < N) {
        int s = offs[r], e = offs[r + 1];
        int loff = l * 16;
        for (int base = s; base < e; base += 32) {
          uint2 ed[8];
#pragma unroll
          for (int q = 0; q < 8; ++q) {
            int i = base + 4 * q + g;
            ed[q] = (i < e) ? ep[i] : make_uint2(0u, 0u);
          }
          uint4 yv[8];
#pragma unroll
          for (int q = 0; q < 8; ++q) yv[q] = *(const uint4*)(Xg + (size_t)(ed[q].x + loff));
#pragma unroll
          for (int q = 0; q < 8; ++q) {
            __half2 f2 = u2h(ed[q].y);
            unsigned uu[4] = {yv[q].x, yv[q].y, yv[q].z, yv[q].w};
#pragma unroll
            for (int k = 0; k < 4; ++k) acc[k] = h2u(__hfma2(u2h(uu[k]), f2, u2h(acc[k])));
          }
        }
#pragma unroll
        for (int k = 0; k < 4; ++k) {
          unsigned a = acc[k];
          unsigned b = (unsigned)__shfl_xor((int)a, 16);
          a = h2u(__hadd2(u2h(a), u2h(b)));
          b = (unsigned)__shfl_xor((int)a, 32);
          a = h2u(__hadd2(u2h(a), u2h(b)));   // no ReLU: z is pre-GEMM
          acc[k] = a;
        }
      }
      if (g == 0) zt[grow][l ^ (grow & 7)] = make_uint4(acc[0], acc[1], acc[2], acc[3]);
    }
  };

  // ---- COMPUTE(h): wave's col-tile mt over half h's 4 row-groups (2 per wave-pair) ----
  auto COMPUTE = [&](int h) {
#pragma unroll
    for (int hh = 0; hh < 2; ++hh) {
      int rg = rgb + 2 * hh;
      int rl = rg * 16 + lr;            // row within half (0..63)
      int grow = h * 64 + rl;
      f16x8 xf[4];
#pragma unroll
      for (int s = 0; s < 4; ++s) {
        uint4 tv = zt[grow][(lk + 4 * s) ^ (grow & 7)];
        xf[s] = *reinterpret_cast<f16x8*>(&tv);
      }
      f32x4 acc = (f32x4){0.f, 0.f, 0.f, 0.f};
#pragma unroll
      for (int s = 0; s < 4; ++s) acc = __builtin_amdgcn_mfma_f32_16x16x32_f16(wf[s], xf[s], acc, 0, 0, 0);
      float ss = 0.f;
#pragma unroll
      for (int q = 0; q < 4; ++q) {
        float y = fmaxf(acc[q], 0.f);
        acc[q] = y;
        ss = fmaf(y, y, ss);
      }
      ss += __shfl_xor(ss, 16);
      ss += __shfl_xor(ss, 32);
      unsigned lo = (unsigned)f2h(acc[0]) | ((unsigned)f2h(acc[1]) << 16);
      unsigned hi = (unsigned)f2h(acc[2]) | ((unsigned)f2h(acc[3]) << 16);
      ytr[h][rl][(mt * 4 + lk) ^ ((lr & 7) << 1)] = make_uint2(lo, hi);
      if (lane < 16) nrmp[h][rl][mt] = ss;
    }
  };

  // ---- STORE(h): wave stores 4 rows (full-line), lane l owns cols 8l..8l+7 ----
  auto STORE = [&](int h) {
    int lrow = wave * 4 + g;            // row within half
    int r = r0g + h * 64 + lrow;
    float np = (l < 8) ? nrmp[h][lrow][l] : 0.f;
    np += __shfl_xor(np, 1);
    np += __shfl_xor(np, 2);
    np += __shfl_xor(np, 4);
    np += __shfl_xor(np, 8);
    int cb = (2 * l) ^ ((lrow & 7) << 1);
    uint4 yy = *(const uint4*)&ytr[h][lrow][cb];   // logical cols 8l..8l+7
    if (r >= N) return;
    if (LAST == 0) {
      *(uint4*)((char*)Xout + (size_t)r * 256 + (size_t)l * 16) = yy;
      if (l == 0) nrmL[r] = sqrtf(np);
    } else {
      size_t pb = (size_t)r * D + l * 8;
      uint4 a0 = *(const uint4*)&x0b[pb];
      unsigned w0[4] = {a0.x, a0.y, a0.z, a0.w};
      float ev[8];
      float se = 0.f;
#pragma unroll
      for (int k = 0; k < 4; ++k) {
        __half2 h0 = u2h(w0[k]);
        ev[2 * k] = __low2float(h0);
        ev[2 * k + 1] = __high2float(h0);
        se = fmaf(ev[2 * k], ev[2 * k], se);
        se = fmaf(ev[2 * k + 1], ev[2 * k + 1], se);
      }
      se += __shfl_xor(se, 1);
      se += __shfl_xor(se, 2);
      se += __shfl_xor(se, 4);
      se += __shfl_xor(se, 8);
      float i0 = scl / fmaxf(sqrtf(se), 1e-12f);
      float i1 = scl / fmaxf(nrm01[r], 1e-12f);
      float i2 = scl / fmaxf(nrm01[N + r], 1e-12f);
      float i3 = scl / fmaxf(sqrtf(np), 1e-12f);
      uint4 a1 = *(const uint4*)&x1b[pb];
      uint4 a2 = *(const uint4*)&x2b[pb];
      unsigned w1[4] = {a1.x, a1.y, a1.z, a1.w};
      unsigned w2[4] = {a2.x, a2.y, a2.z, a2.w};
      unsigned w3[4] = {yy.x, yy.y, yy.z, yy.w};
      float o[8];
#pragma unroll
      for (int k = 0; k < 4; ++k) {
        __half2 h1 = u2h(w1[k]), h2v = u2h(w2[k]), h3 = u2h(w3[k]);
        o[2 * k]     = i0 * ev[2 * k]     + i1 * __low2float(h1)  + i2 * __low2float(h2v)  + i3 * __low2float(h3);
        o[2 * k + 1] = i0 * ev[2 * k + 1] + i1 * __high2float(h1) + i2 * __high2float(h2v) + i3 * __high2float(h3);
      }
      *(float4*)&outp[pb]     = make_float4(o[0], o[1], o[2], o[3]);
      *(float4*)&outp[pb + 4] = make_float4(o[4], o[5], o[6], o[7]);
    }
  };

  GATHER(0);
  __syncthreads();
  COMPUTE(0);          // MFMA on half 0 ...
  GATHER(1);           // ... overlapped (issue-wise) with half-1 gather
  __syncthreads();
  STORE(0);            // stores of half 0 ...
  COMPUTE(1);          // ... overlapped with half-1 MFMA
  __syncthreads();
  STORE(1);
}

// ---------------- launch ----------------
extern "C" void kernel_launch(void* const* d_in, const int* in_sizes, int n_in,
                              void* d_out, int out_size, void* d_ws, size_t ws_size,
                              hipStream_t stream) {
  const int* rows = (const int*)d_in[0];
  const int* cols = (const int*)d_in[1];
  const float* vals = (const float*)d_in[2];
  const float* emb = (const float*)d_in[3];
  const float* W = (const float*)d_in[4];
  float* out = (float*)d_out;

  int E = in_sizes[0];
  int N = in_sizes[3] / D;
  int L = in_sizes[4] / (D * D);
  float scl = 1.0f / (float)(L + 1);

  int bshift = 10;
  int NBUCK = (N + (1 << bshift) - 1) >> bshift;

  int per = 4096;
  while ((E + per - 1) / per > 512) per *= 2;
  int NW = (E + per - 1) / per;

  char* ws = (char*)d_ws;
  size_t off = 0;
  auto take = [&](size_t bytes) -> void* {
    void* p = ws + off;
    off += (bytes + 255) & ~(size_t)255;
    return p;
  };
  unsigned short* xb0 = (unsigned short*)take((size_t)N * D * 2);   // fp16 emb
  unsigned short* xb1 = (unsigned short*)take((size_t)N * D * 2);
  unsigned short* xb2 = (unsigned short*)take((size_t)N * D * 2);
  unsigned short* wb  = (unsigned short*)take((size_t)L * D * D * 2);
  float* nrm = (float*)take((size_t)2 * N * sizeof(float));
  int* offsets = (int*)take((size_t)(N + 1) * 4);
  int* wghist = (int*)take((size_t)NBUCK_MAX * NW * 4);
  int* wgstart = (int*)take((size_t)NBUCK_MAX * NW * 4);
  int* btot = (int*)take((size_t)NBUCK_MAX * 4);
  uint2* ep = (uint2*)take((size_t)(E + 32) * 8);
  // gbin aliases xb1: consumed (debin2) strictly before spgemm layer 0 writes xb1 (stream-ordered)
  uint2* gbin = (uint2*)xb1;

  // radix partition into buckets, then per-bucket offsets + scatter
  wg_hist<<<NW, 256, 0, stream>>>(rows, wghist, E, NW, per, bshift);
  scan_wg<<<NBUCK, 512, 0, stream>>>(wghist, wgstart, btot, NW);
  partition_kernel<<<NW, 256, 0, stream>>>(rows, cols, vals, wgstart, btot, gbin, E, NW, per, bshift);
  debin2<<<NBUCK, 256, 0, stream>>>(gbin, btot, offsets, ep, N, E, bshift, NBUCK);

  // fp16 conversions (emb + W, one launch)
  int n8x = N * D / 8;
  int n8w = L * D * D / 8;
  conv_f16<<<(n8x + n8w + 255) / 256, 256, 0, stream>>>(emb, xb0, W, wb, n8x, n8x + n8w);

  int nb128 = (N + 127) / 128;
  // layer 0: gather xb0 -> x1
  spgemm_kernel<0><<<nb128, 1024, 0, stream>>>((const char*)xb0, wb, offsets, ep,
                                               xb1, nrm, nullptr, nullptr, nullptr, nullptr, nullptr, N, scl);
  // layer 1: gather xb1 -> x2
  spgemm_kernel<0><<<nb128, 1024, 0, stream>>>((const char*)xb1, wb + (size_t)D * D, offsets, ep,
                                               xb2, nrm + N, nullptr, nullptr, nullptr, nullptr, nullptr, N, scl);
  // layer 2: gather xb2, fused final combine -> out
  spgemm_kernel<1><<<nb128, 1024, 0, stream>>>((const char*)xb2, wb + (size_t)2 * D * D, offsets, ep,
                                               nullptr, nullptr, xb0, xb1, xb2, nrm, out, N, scl);
}

// Round 18
// 298.413 us; speedup vs baseline: 1.5018x; 1.5018x over previous
//
#include <hip/hip_runtime.h>
#include <hip/hip_fp16.h>
#include <math.h>

#define D 128
#define NBUCK_MAX 128
#define BROWS 1024   // rows per bucket (bshift=10); requires N <= 131072 (col packs in 17 bits)

typedef _Float16 f16x8 __attribute__((ext_vector_type(8)));
typedef __attribute__((ext_vector_type(4))) float f32x4;

static __device__ __forceinline__ unsigned short f2h(float f) {
  __half h = __float2half(f);
  return *reinterpret_cast<unsigned short*>(&h);
}
static __device__ __forceinline__ __half2 u2h(unsigned u) { return *reinterpret_cast<__half2*>(&u); }
static __device__ __forceinline__ unsigned h2u(__half2 h) { return *reinterpret_cast<unsigned*>(&h); }

// ---- radix partition by bucket (row >> bshift), WG-private histograms ----
__global__ __launch_bounds__(256) void wg_hist(const int* __restrict__ rows, int* __restrict__ wghist,
                                               int E, int NW, int per, int bshift) {
  __shared__ int cnt[NBUCK_MAX];
  int tid = threadIdx.x, w = blockIdx.x;
  if (tid < NBUCK_MAX) cnt[tid] = 0;
  __syncthreads();
  int base = w * per;
  int end = base + per; if (end > E) end = E;
  for (int e = base + tid; e < end; e += 256) atomicAdd(&cnt[rows[e] >> bshift], 1);
  __syncthreads();
  if (tid < NBUCK_MAX) wghist[tid * NW + w] = cnt[tid];
}

__global__ __launch_bounds__(512) void scan_wg(const int* __restrict__ wghist, int* __restrict__ wgstart,
                                               int* __restrict__ btot, int NW) {
  int b = blockIdx.x, t = threadIdx.x;
  __shared__ int s[512];
  int v = (t < NW) ? wghist[b * NW + t] : 0;
  s[t] = v;
  __syncthreads();
  for (int d = 1; d < 512; d <<= 1) {
    int x = (t >= d) ? s[t - d] : 0;
    __syncthreads();
    s[t] += x;
    __syncthreads();
  }
  if (t < NW) wgstart[b * NW + t] = s[t] - v;
  if (t == 511) btot[b] = s[511];
}

// inclusive 128-wide prefix of btot into bp[] (LDS); call with >=128 threads, all hitting barriers
static __device__ __forceinline__ void scan_btot_lds(const int* __restrict__ btot, int* bp, int tid) {
  if (tid < NBUCK_MAX) bp[tid] = btot[tid];
  __syncthreads();
  for (int d = 1; d < NBUCK_MAX; d <<= 1) {
    int x = (tid >= d && tid < NBUCK_MAX) ? bp[tid - d] : 0;
    __syncthreads();
    if (tid < NBUCK_MAX) bp[tid] += x;
    __syncthreads();
  }
}

__global__ __launch_bounds__(256) void partition_kernel(const int* __restrict__ rows, const int* __restrict__ cols,
                                                        const float* __restrict__ vals, const int* __restrict__ wgstart,
                                                        const int* __restrict__ btot,
                                                        uint2* __restrict__ gbin, int E, int NW, int per, int bshift) {
  __shared__ int bp[NBUCK_MAX];
  __shared__ int cur[NBUCK_MAX];
  int tid = threadIdx.x, w = blockIdx.x;
  scan_btot_lds(btot, bp, tid);
  if (tid < NBUCK_MAX) cur[tid] = (tid ? bp[tid - 1] : 0) + wgstart[tid * NW + w];
  __syncthreads();
  unsigned rmask = (1u << bshift) - 1u;
  int base = w * per;
  int end = base + per; if (end > E) end = E;
  for (int e = base + tid; e < end; e += 256) {
    unsigned r = (unsigned)rows[e];
    int b = r >> bshift;
    int pos = atomicAdd(&cur[b], 1);
    gbin[pos] = make_uint2(((r & rmask) << 17) | (unsigned)cols[e], __float_as_uint(vals[e]));
  }
}

// per-bucket: LDS row-histogram + scan -> row offsets; scatter into final CSR ep
// ep entry: .x = gather-row byte offset (col*256), .y = val as packed half2 (h | h<<16)
__global__ __launch_bounds__(256) void debin2(const uint2* __restrict__ gbin, const int* __restrict__ btot,
                                              int* __restrict__ offsets, uint2* __restrict__ ep,
                                              int N, int E, int bshift, int NBUCK) {
  __shared__ int bp[NBUCK_MAX];
  __shared__ int cnt[BROWS];
  __shared__ int sblk[256];
  int b = blockIdx.x, t = threadIdx.x;
  scan_btot_lds(btot, bp, t);
  int s0 = (b ? bp[b - 1] : 0), e0 = bp[b];
  int r0 = b << bshift;
  int r1 = r0 + BROWS; if (r1 > N) r1 = N;
  int nr = r1 - r0;
#pragma unroll
  for (int q = 0; q < 4; ++q) cnt[t * 4 + q] = 0;
  __syncthreads();
  for (int i = s0 + t; i < e0; i += 256) atomicAdd(&cnt[gbin[i].x >> 17], 1);
  __syncthreads();
  int c[4]; int tsum = 0;
#pragma unroll
  for (int q = 0; q < 4; ++q) { c[q] = cnt[4 * t + q]; tsum += c[q]; }
  sblk[t] = tsum;
  __syncthreads();
  for (int d = 1; d < 256; d <<= 1) {
    int x = (t >= d) ? sblk[t - d] : 0;
    __syncthreads();
    sblk[t] += x;
    __syncthreads();
  }
  int run = s0 + sblk[t] - tsum;
#pragma unroll
  for (int q = 0; q < 4; ++q) {
    int j = 4 * t + q;
    if (j < nr) offsets[r0 + j] = run;
    cnt[j] = run;   // reuse as absolute cursor
    run += c[q];
  }
  __syncthreads();
  for (int i = s0 + t; i < e0; i += 256) {
    uint2 en = gbin[i];
    int lr = (int)(en.x >> 17);
    int pos = atomicAdd(&cnt[lr], 1);
    unsigned short h = f2h(__uint_as_float(en.y));
    ep[pos] = make_uint2((en.x & 0x1FFFFu) << 8, ((unsigned)h << 16) | (unsigned)h);
  }
  if (b == NBUCK - 1 && t == 0) offsets[N] = E;
}

// ---------------- fp32 -> fp16 converter (emb and W in one launch) ----------------
__global__ __launch_bounds__(256) void conv_f16(const float* __restrict__ a, unsigned short* __restrict__ oa,
                                                const float* __restrict__ bsrc, unsigned short* __restrict__ ob,
                                                int n8a, int n8tot) {
  int t = blockIdx.x * 256 + threadIdx.x;
  if (t >= n8tot) return;
  const float* src = (t < n8a) ? a : bsrc;
  unsigned short* dst = (t < n8a) ? oa : ob;
  int idx = (t < n8a) ? t : t - n8a;
  size_t base = (size_t)idx * 8;
  float4 x = *(const float4*)&src[base];
  float4 y = *(const float4*)&src[base + 4];
  ushort4 o0, o1;
  o0.x = f2h(x.x); o0.y = f2h(x.y); o0.z = f2h(x.z); o0.w = f2h(x.w);
  o1.x = f2h(y.x); o1.y = f2h(y.y); o1.z = f2h(y.z); o1.w = f2h(y.w);
  *(ushort4*)&dst[base] = o0;
  *(ushort4*)&dst[base + 4] = o1;
}

// ---------------- fused layer v5: 64 rows/block, 512 threads, 8 waves — high occupancy ----------------
// (A·(x·Wᵀ)) == ((A·x)·Wᵀ). R16 structure, halved block: LDS 34.3KB -> 4 blocks/CU (32 waves/CU).
// Cross-block phase overlap replaces R17's (spill-inducing) intra-wave pipeline.
// Phase 1: wave w gathers rows [w*8, w*8+8) serially (proven 32-edge-deep loop) -> zt (swizzled).
// Phase 2: wave w owns col-tile mt=w; 4 row-groups; W frag in 16 VGPRs; MFMA+ReLU -> ytr, norms.
// Phase 3: row-parallel full-line stores; LAST=1 fuses combine (fp16 x0 term) -> fp32 out.
template <int LAST>
__global__ __launch_bounds__(512, 8) void spgemm_kernel(
    const char* __restrict__ Xg, const unsigned short* __restrict__ wb,
    const int* __restrict__ offs, const uint2* __restrict__ ep,
    unsigned short* __restrict__ Xout, float* __restrict__ nrmL,
    const unsigned short* __restrict__ x0b, const unsigned short* __restrict__ x1b,
    const unsigned short* __restrict__ x2b, const float* __restrict__ nrm01,
    float* __restrict__ outp, int N, float scl) {
  __shared__ uint4 zt[64][16];     // z rows (f16), chunk c stored at c ^ (row&7)
  __shared__ uint2 ytr[64][32];    // y rows (f16), uint2-chunk c stored at c ^ ((row&7)<<1)
  __shared__ float nrmp[64][9];    // per-(row, mt) partial ||y||^2
  int tid = threadIdx.x;
  int wave = tid >> 6, lane = tid & 63;
  int g = lane >> 4, l = lane & 15;
  int r0g = blockIdx.x * 64;
  // ---- phase 1: gather 8 rows per wave (f16 packed accum, guarded loads) ----
  for (int j = 0; j < 8; ++j) {
    int lrow = wave * 8 + j;
    int r = r0g + lrow;
    unsigned acc[4] = {0u, 0u, 0u, 0u};
    if (r < N) {
      int s = offs[r], e = offs[r + 1];
      int loff = l * 16;
      for (int base = s; base < e; base += 32) {
        uint2 ed[8];
#pragma unroll
        for (int q = 0; q < 8; ++q) {
          int i = base + 4 * q + g;
          ed[q] = (i < e) ? ep[i] : make_uint2(0u, 0u);
        }
        uint4 yv[8];
#pragma unroll
        for (int q = 0; q < 8; ++q) yv[q] = *(const uint4*)(Xg + (size_t)(ed[q].x + loff));
#pragma unroll
        for (int q = 0; q < 8; ++q) {
          __half2 f2 = u2h(ed[q].y);
          unsigned uu[4] = {yv[q].x, yv[q].y, yv[q].z, yv[q].w};
#pragma unroll
          for (int k = 0; k < 4; ++k) acc[k] = h2u(__hfma2(u2h(uu[k]), f2, u2h(acc[k])));
        }
      }
#pragma unroll
      for (int k = 0; k < 4; ++k) {
        unsigned a = acc[k];
        unsigned b = (unsigned)__shfl_xor((int)a, 16);
        a = h2u(__hadd2(u2h(a), u2h(b)));
        b = (unsigned)__shfl_xor((int)a, 32);
        a = h2u(__hadd2(u2h(a), u2h(b)));   // no ReLU: z is pre-GEMM
        acc[k] = a;
      }
    }
    if (g == 0) zt[lrow][l ^ (lrow & 7)] = make_uint4(acc[0], acc[1], acc[2], acc[3]);
  }
  __syncthreads();
  // ---- phase 2: MFMA col-tile mt = wave over 4 row-groups; W cached in regs ----
  {
    int lr = lane & 15, lk = lane >> 4;
    int mt = wave;
    const unsigned short* wbase = wb + (size_t)(mt * 16 + lr) * D + lk * 8;
    f16x8 wf[4];
#pragma unroll
    for (int s = 0; s < 4; ++s) wf[s] = *(const f16x8*)(wbase + 32 * s);
#pragma unroll
    for (int h = 0; h < 4; ++h) {
      int rl = h * 16 + lr;
      f16x8 xf[4];
#pragma unroll
      for (int s = 0; s < 4; ++s) {
        uint4 tv = zt[rl][(lk + 4 * s) ^ (lr & 7)];
        xf[s] = *reinterpret_cast<f16x8*>(&tv);
      }
      f32x4 acc = (f32x4){0.f, 0.f, 0.f, 0.f};
#pragma unroll
      for (int s = 0; s < 4; ++s) acc = __builtin_amdgcn_mfma_f32_16x16x32_f16(wf[s], xf[s], acc, 0, 0, 0);
      float ss = 0.f;
#pragma unroll
      for (int q = 0; q < 4; ++q) {
        float y = fmaxf(acc[q], 0.f);
        acc[q] = y;
        ss = fmaf(y, y, ss);
      }
      ss += __shfl_xor(ss, 16);
      ss += __shfl_xor(ss, 32);
      unsigned lo = (unsigned)f2h(acc[0]) | ((unsigned)f2h(acc[1]) << 16);
      unsigned hi = (unsigned)f2h(acc[2]) | ((unsigned)f2h(acc[3]) << 16);
      ytr[rl][(mt * 4 + lk) ^ ((lr & 7) << 1)] = make_uint2(lo, hi);
      if (lane < 16) nrmp[rl][mt] = ss;
    }
  }
  __syncthreads();
  // ---- phase 3: row-parallel output (full-line stores, lane l owns cols 8l..8l+7) ----
  for (int it = 0; it < 2; ++it) {
    int lrow = wave * 8 + it * 4 + g;
    int r = r0g + lrow;
    float np = (l < 8) ? nrmp[lrow][l] : 0.f;
    np += __shfl_xor(np, 1);
    np += __shfl_xor(np, 2);
    np += __shfl_xor(np, 4);
    np += __shfl_xor(np, 8);
    int cb = (2 * l) ^ ((lrow & 7) << 1);
    uint4 yy = *(const uint4*)&ytr[lrow][cb];   // logical cols 8l..8l+7
    if (r >= N) continue;
    if (LAST == 0) {
      *(uint4*)((char*)Xout + (size_t)r * 256 + (size_t)l * 16) = yy;
      if (l == 0) nrmL[r] = sqrtf(np);
    } else {
      size_t pb = (size_t)r * D + l * 8;
      uint4 a0 = *(const uint4*)&x0b[pb];
      unsigned w0[4] = {a0.x, a0.y, a0.z, a0.w};
      float ev[8];
      float se = 0.f;
#pragma unroll
      for (int k = 0; k < 4; ++k) {
        __half2 h0 = u2h(w0[k]);
        ev[2 * k] = __low2float(h0);
        ev[2 * k + 1] = __high2float(h0);
        se = fmaf(ev[2 * k], ev[2 * k], se);
        se = fmaf(ev[2 * k + 1], ev[2 * k + 1], se);
      }
      se += __shfl_xor(se, 1);
      se += __shfl_xor(se, 2);
      se += __shfl_xor(se, 4);
      se += __shfl_xor(se, 8);
      float i0 = scl / fmaxf(sqrtf(se), 1e-12f);
      float i1 = scl / fmaxf(nrm01[r], 1e-12f);
      float i2 = scl / fmaxf(nrm01[N + r], 1e-12f);
      float i3 = scl / fmaxf(sqrtf(np), 1e-12f);
      uint4 a1 = *(const uint4*)&x1b[pb];
      uint4 a2 = *(const uint4*)&x2b[pb];
      unsigned w1[4] = {a1.x, a1.y, a1.z, a1.w};
      unsigned w2[4] = {a2.x, a2.y, a2.z, a2.w};
      unsigned w3[4] = {yy.x, yy.y, yy.z, yy.w};
      float o[8];
#pragma unroll
      for (int k = 0; k < 4; ++k) {
        __half2 h1 = u2h(w1[k]), h2v = u2h(w2[k]), h3 = u2h(w3[k]);
        o[2 * k]     = i0 * ev[2 * k]     + i1 * __low2float(h1)  + i2 * __low2float(h2v)  + i3 * __low2float(h3);
        o[2 * k + 1] = i0 * ev[2 * k + 1] + i1 * __high2float(h1) + i2 * __high2float(h2v) + i3 * __high2float(h3);
      }
      *(float4*)&outp[pb]     = make_float4(o[0], o[1], o[2], o[3]);
      *(float4*)&outp[pb + 4] = make_float4(o[4], o[5], o[6], o[7]);
    }
  }
}

// ---------------- launch ----------------
extern "C" void kernel_launch(void* const* d_in, const int* in_sizes, int n_in,
                              void* d_out, int out_size, void* d_ws, size_t ws_size,
                              hipStream_t stream) {
  const int* rows = (const int*)d_in[0];
  const int* cols = (const int*)d_in[1];
  const float* vals = (const float*)d_in[2];
  const float* emb = (const float*)d_in[3];
  const float* W = (const float*)d_in[4];
  float* out = (float*)d_out;

  int E = in_sizes[0];
  int N = in_sizes[3] / D;
  int L = in_sizes[4] / (D * D);
  float scl = 1.0f / (float)(L + 1);

  int bshift = 10;
  int NBUCK = (N + (1 << bshift) - 1) >> bshift;

  int per = 4096;
  while ((E + per - 1) / per > 512) per *= 2;
  int NW = (E + per - 1) / per;

  char* ws = (char*)d_ws;
  size_t off = 0;
  auto take = [&](size_t bytes) -> void* {
    void* p = ws + off;
    off += (bytes + 255) & ~(size_t)255;
    return p;
  };
  unsigned short* xb0 = (unsigned short*)take((size_t)N * D * 2);   // fp16 emb
  unsigned short* xb1 = (unsigned short*)take((size_t)N * D * 2);
  unsigned short* xb2 = (unsigned short*)take((size_t)N * D * 2);
  unsigned short* wb  = (unsigned short*)take((size_t)L * D * D * 2);
  float* nrm = (float*)take((size_t)2 * N * sizeof(float));
  int* offsets = (int*)take((size_t)(N + 1) * 4);
  int* wghist = (int*)take((size_t)NBUCK_MAX * NW * 4);
  int* wgstart = (int*)take((size_t)NBUCK_MAX * NW * 4);
  int* btot = (int*)take((size_t)NBUCK_MAX * 4);
  uint2* ep = (uint2*)take((size_t)(E + 32) * 8);
  // gbin aliases xb1: consumed (debin2) strictly before spgemm layer 0 writes xb1 (stream-ordered)
  uint2* gbin = (uint2*)xb1;

  // radix partition into buckets, then per-bucket offsets + scatter
  wg_hist<<<NW, 256, 0, stream>>>(rows, wghist, E, NW, per, bshift);
  scan_wg<<<NBUCK, 512, 0, stream>>>(wghist, wgstart, btot, NW);
  partition_kernel<<<NW, 256, 0, stream>>>(rows, cols, vals, wgstart, btot, gbin, E, NW, per, bshift);
  debin2<<<NBUCK, 256, 0, stream>>>(gbin, btot, offsets, ep, N, E, bshift, NBUCK);

  // fp16 conversions (emb + W, one launch)
  int n8x = N * D / 8;
  int n8w = L * D * D / 8;
  conv_f16<<<(n8x + n8w + 255) / 256, 256, 0, stream>>>(emb, xb0, W, wb, n8x, n8x + n8w);

  int nb64 = (N + 63) / 64;
  // layer 0: gather xb0 -> x1
  spgemm_kernel<0><<<nb64, 512, 0, stream>>>((const char*)xb0, wb, offsets, ep,
                                             xb1, nrm, nullptr, nullptr, nullptr, nullptr, nullptr, N, scl);
  // layer 1: gather xb1 -> x2
  spgemm_kernel<0><<<nb64, 512, 0, stream>>>((const char*)xb1, wb + (size_t)D * D, offsets, ep,
                                             xb2, nrm + N, nullptr, nullptr, nullptr, nullptr, nullptr, N, scl);
  // layer 2: gather xb2, fused final combine -> out
  spgemm_kernel<1><<<nb64, 512, 0, stream>>>((const char*)xb2, wb + (size_t)2 * D * D, offsets, ep,
                                             nullptr, nullptr, xb0, xb1, xb2, nrm, out, N, scl);
}

// Round 19
// 293.376 us; speedup vs baseline: 1.5276x; 1.0172x over previous
//
#include <hip/hip_runtime.h>
#include <hip/hip_fp16.h>
#include <math.h>

#define D 128
#define NBUCK_MAX 128
#define BROWS 1024   // rows per bucket (bshift=10); requires N <= 131072 (col packs in 17 bits)

typedef _Float16 f16x8 __attribute__((ext_vector_type(8)));
typedef __attribute__((ext_vector_type(4))) float f32x4;

static __device__ __forceinline__ unsigned short f2h(float f) {
  __half h = __float2half(f);
  return *reinterpret_cast<unsigned short*>(&h);
}
static __device__ __forceinline__ __half2 u2h(unsigned u) { return *reinterpret_cast<__half2*>(&u); }
static __device__ __forceinline__ unsigned h2u(__half2 h) { return *reinterpret_cast<unsigned*>(&h); }

// ---- fused: blocks [0,NW) = per-WG bucket histogram; blocks [NW, NW+CB) = fp32->fp16 conversion ----
__global__ __launch_bounds__(256) void hist_conv(const int* __restrict__ rows, int* __restrict__ wghist,
                                                 int E, int NW, int per, int bshift,
                                                 const float* __restrict__ ca, unsigned short* __restrict__ oa,
                                                 const float* __restrict__ cb, unsigned short* __restrict__ ob,
                                                 int n8a, int n8tot) {
  int w = blockIdx.x;
  if (w < NW) {
    __shared__ int cnt[NBUCK_MAX];
    int tid = threadIdx.x;
    if (tid < NBUCK_MAX) cnt[tid] = 0;
    __syncthreads();
    int base = w * per;
    int end = base + per; if (end > E) end = E;
    for (int e = base + tid; e < end; e += 256) atomicAdd(&cnt[rows[e] >> bshift], 1);
    __syncthreads();
    if (tid < NBUCK_MAX) wghist[tid * NW + w] = cnt[tid];
  } else {
    int t = (w - NW) * 256 + threadIdx.x;
    if (t >= n8tot) return;
    const float* src = (t < n8a) ? ca : cb;
    unsigned short* dst = (t < n8a) ? oa : ob;
    int idx = (t < n8a) ? t : t - n8a;
    size_t base = (size_t)idx * 8;
    float4 x = *(const float4*)&src[base];
    float4 y = *(const float4*)&src[base + 4];
    ushort4 o0, o1;
    o0.x = f2h(x.x); o0.y = f2h(x.y); o0.z = f2h(x.z); o0.w = f2h(x.w);
    o1.x = f2h(y.x); o1.y = f2h(y.y); o1.z = f2h(y.z); o1.w = f2h(y.w);
    *(ushort4*)&dst[base] = o0;
    *(ushort4*)&dst[base + 4] = o1;
  }
}

__global__ __launch_bounds__(512) void scan_wg(const int* __restrict__ wghist, int* __restrict__ wgstart,
                                               int* __restrict__ btot, int NW) {
  int b = blockIdx.x, t = threadIdx.x;
  __shared__ int s[512];
  int v = (t < NW) ? wghist[b * NW + t] : 0;
  s[t] = v;
  __syncthreads();
  for (int d = 1; d < 512; d <<= 1) {
    int x = (t >= d) ? s[t - d] : 0;
    __syncthreads();
    s[t] += x;
    __syncthreads();
  }
  if (t < NW) wgstart[b * NW + t] = s[t] - v;
  if (t == 511) btot[b] = s[511];
}

// inclusive 128-wide prefix of btot into bp[] (LDS); call with >=128 threads, all hitting barriers
static __device__ __forceinline__ void scan_btot_lds(const int* __restrict__ btot, int* bp, int tid) {
  if (tid < NBUCK_MAX) bp[tid] = btot[tid];
  __syncthreads();
  for (int d = 1; d < NBUCK_MAX; d <<= 1) {
    int x = (tid >= d && tid < NBUCK_MAX) ? bp[tid - d] : 0;
    __syncthreads();
    if (tid < NBUCK_MAX) bp[tid] += x;
    __syncthreads();
  }
}

__global__ __launch_bounds__(256) void partition_kernel(const int* __restrict__ rows, const int* __restrict__ cols,
                                                        const float* __restrict__ vals, const int* __restrict__ wgstart,
                                                        const int* __restrict__ btot,
                                                        uint2* __restrict__ gbin, int E, int NW, int per, int bshift) {
  __shared__ int bp[NBUCK_MAX];
  __shared__ int cur[NBUCK_MAX];
  int tid = threadIdx.x, w = blockIdx.x;
  scan_btot_lds(btot, bp, tid);
  if (tid < NBUCK_MAX) cur[tid] = (tid ? bp[tid - 1] : 0) + wgstart[tid * NW + w];
  __syncthreads();
  unsigned rmask = (1u << bshift) - 1u;
  int base = w * per;
  int end = base + per; if (end > E) end = E;
  for (int e = base + tid; e < end; e += 256) {
    unsigned r = (unsigned)rows[e];
    int b = r >> bshift;
    int pos = atomicAdd(&cur[b], 1);
    gbin[pos] = make_uint2(((r & rmask) << 17) | (unsigned)cols[e], __float_as_uint(vals[e]));
  }
}

// per-bucket: LDS row-histogram + scan -> row offsets; scatter into final CSR ep
// ep entry: .x = gather-row byte offset (col*256), .y = val as packed half2 (h | h<<16)
__global__ __launch_bounds__(256) void debin2(const uint2* __restrict__ gbin, const int* __restrict__ btot,
                                              int* __restrict__ offsets, uint2* __restrict__ ep,
                                              int N, int E, int bshift, int NBUCK) {
  __shared__ int bp[NBUCK_MAX];
  __shared__ int cnt[BROWS];
  __shared__ int sblk[256];
  int b = blockIdx.x, t = threadIdx.x;
  scan_btot_lds(btot, bp, t);
  int s0 = (b ? bp[b - 1] : 0), e0 = bp[b];
  int r0 = b << bshift;
  int r1 = r0 + BROWS; if (r1 > N) r1 = N;
  int nr = r1 - r0;
#pragma unroll
  for (int q = 0; q < 4; ++q) cnt[t * 4 + q] = 0;
  __syncthreads();
  for (int i = s0 + t; i < e0; i += 256) atomicAdd(&cnt[gbin[i].x >> 17], 1);
  __syncthreads();
  int c[4]; int tsum = 0;
#pragma unroll
  for (int q = 0; q < 4; ++q) { c[q] = cnt[4 * t + q]; tsum += c[q]; }
  sblk[t] = tsum;
  __syncthreads();
  for (int d = 1; d < 256; d <<= 1) {
    int x = (t >= d) ? sblk[t - d] : 0;
    __syncthreads();
    sblk[t] += x;
    __syncthreads();
  }
  int run = s0 + sblk[t] - tsum;
#pragma unroll
  for (int q = 0; q < 4; ++q) {
    int j = 4 * t + q;
    if (j < nr) offsets[r0 + j] = run;
    cnt[j] = run;   // reuse as absolute cursor
    run += c[q];
  }
  __syncthreads();
  for (int i = s0 + t; i < e0; i += 256) {
    uint2 en = gbin[i];
    int lr = (int)(en.x >> 17);
    int pos = atomicAdd(&cnt[lr], 1);
    unsigned short h = f2h(__uint_as_float(en.y));
    ep[pos] = make_uint2((en.x & 0x1FFFFu) << 8, ((unsigned)h << 16) | (unsigned)h);
  }
  if (b == NBUCK - 1 && t == 0) offsets[N] = E;
}

// ---------------- fused layer v6: 64 rows/block, 512 threads, work-stealing gather ----------------
// (A·(x·Wᵀ)) == ((A·x)·Wᵀ). As R18 (4 blocks/CU) plus an LDS row counter: waves steal rows until
// the block's 64 are done -> barrier waits on the last row, not the worst static 8-row bundle.
// Phase 2: wave w owns col-tile mt=w; W frag in 16 VGPRs; MFMA+ReLU -> ytr, norms.
// Phase 3: row-parallel full-line stores; LAST=1 fuses combine (fp16 x0 term) -> fp32 out.
template <int LAST>
__global__ __launch_bounds__(512, 8) void spgemm_kernel(
    const char* __restrict__ Xg, const unsigned short* __restrict__ wb,
    const int* __restrict__ offs, const uint2* __restrict__ ep,
    unsigned short* __restrict__ Xout, float* __restrict__ nrmL,
    const unsigned short* __restrict__ x0b, const unsigned short* __restrict__ x1b,
    const unsigned short* __restrict__ x2b, const float* __restrict__ nrm01,
    float* __restrict__ outp, int N, float scl) {
  __shared__ uint4 zt[64][16];     // z rows (f16), chunk c stored at c ^ (row&7)
  __shared__ uint2 ytr[64][32];    // y rows (f16), uint2-chunk c stored at c ^ ((row&7)<<1)
  __shared__ float nrmp[64][9];    // per-(row, mt) partial ||y||^2
  __shared__ int rowctr;
  int tid = threadIdx.x;
  int wave = tid >> 6, lane = tid & 63;
  int g = lane >> 4, l = lane & 15;
  int r0g = blockIdx.x * 64;
  if (tid == 0) rowctr = 0;
  __syncthreads();
  // ---- phase 1: work-stealing gather (f16 packed accum, guarded loads) ----
  for (;;) {
    int lrow = 0;
    if (lane == 0) lrow = atomicAdd(&rowctr, 1);
    lrow = __shfl(lrow, 0);
    if (lrow >= 64) break;
    int r = r0g + lrow;
    unsigned acc[4] = {0u, 0u, 0u, 0u};
    if (r < N) {
      int s = offs[r], e = offs[r + 1];
      int loff = l * 16;
      for (int base = s; base < e; base += 32) {
        uint2 ed[8];
#pragma unroll
        for (int q = 0; q < 8; ++q) {
          int i = base + 4 * q + g;
          ed[q] = (i < e) ? ep[i] : make_uint2(0u, 0u);
        }
        uint4 yv[8];
#pragma unroll
        for (int q = 0; q < 8; ++q) yv[q] = *(const uint4*)(Xg + (size_t)(ed[q].x + loff));
#pragma unroll
        for (int q = 0; q < 8; ++q) {
          __half2 f2 = u2h(ed[q].y);
          unsigned uu[4] = {yv[q].x, yv[q].y, yv[q].z, yv[q].w};
#pragma unroll
          for (int k = 0; k < 4; ++k) acc[k] = h2u(__hfma2(u2h(uu[k]), f2, u2h(acc[k])));
        }
      }
#pragma unroll
      for (int k = 0; k < 4; ++k) {
        unsigned a = acc[k];
        unsigned b = (unsigned)__shfl_xor((int)a, 16);
        a = h2u(__hadd2(u2h(a), u2h(b)));
        b = (unsigned)__shfl_xor((int)a, 32);
        a = h2u(__hadd2(u2h(a), u2h(b)));   // no ReLU: z is pre-GEMM
        acc[k] = a;
      }
    }
    if (g == 0) zt[lrow][l ^ (lrow & 7)] = make_uint4(acc[0], acc[1], acc[2], acc[3]);
  }
  __syncthreads();
  // ---- phase 2: MFMA col-tile mt = wave over 4 row-groups; W cached in regs ----
  {
    int lr = lane & 15, lk = lane >> 4;
    int mt = wave;
    const unsigned short* wbase = wb + (size_t)(mt * 16 + lr) * D + lk * 8;
    f16x8 wf[4];
#pragma unroll
    for (int s = 0; s < 4; ++s) wf[s] = *(const f16x8*)(wbase + 32 * s);
#pragma unroll
    for (int h = 0; h < 4; ++h) {
      int rl = h * 16 + lr;
      f16x8 xf[4];
#pragma unroll
      for (int s = 0; s < 4; ++s) {
        uint4 tv = zt[rl][(lk + 4 * s) ^ (lr & 7)];
        xf[s] = *reinterpret_cast<f16x8*>(&tv);
      }
      f32x4 acc = (f32x4){0.f, 0.f, 0.f, 0.f};
#pragma unroll
      for (int s = 0; s < 4; ++s) acc = __builtin_amdgcn_mfma_f32_16x16x32_f16(wf[s], xf[s], acc, 0, 0, 0);
      float ss = 0.f;
#pragma unroll
      for (int q = 0; q < 4; ++q) {
        float y = fmaxf(acc[q], 0.f);
        acc[q] = y;
        ss = fmaf(y, y, ss);
      }
      ss += __shfl_xor(ss, 16);
      ss += __shfl_xor(ss, 32);
      unsigned lo = (unsigned)f2h(acc[0]) | ((unsigned)f2h(acc[1]) << 16);
      unsigned hi = (unsigned)f2h(acc[2]) | ((unsigned)f2h(acc[3]) << 16);
      ytr[rl][(mt * 4 + lk) ^ ((lr & 7) << 1)] = make_uint2(lo, hi);
      if (lane < 16) nrmp[rl][mt] = ss;
    }
  }
  __syncthreads();
  // ---- phase 3: row-parallel output (full-line stores, lane l owns cols 8l..8l+7) ----
  for (int it = 0; it < 2; ++it) {
    int lrow = wave * 8 + it * 4 + g;
    int r = r0g + lrow;
    float np = (l < 8) ? nrmp[lrow][l] : 0.f;
    np += __shfl_xor(np, 1);
    np += __shfl_xor(np, 2);
    np += __shfl_xor(np, 4);
    np += __shfl_xor(np, 8);
    int cb = (2 * l) ^ ((lrow & 7) << 1);
    uint4 yy = *(const uint4*)&ytr[lrow][cb];   // logical cols 8l..8l+7
    if (r >= N) continue;
    if (LAST == 0) {
      *(uint4*)((char*)Xout + (size_t)r * 256 + (size_t)l * 16) = yy;
      if (l == 0) nrmL[r] = sqrtf(np);
    } else {
      size_t pb = (size_t)r * D + l * 8;
      uint4 a0 = *(const uint4*)&x0b[pb];
      unsigned w0[4] = {a0.x, a0.y, a0.z, a0.w};
      float ev[8];
      float se = 0.f;
#pragma unroll
      for (int k = 0; k < 4; ++k) {
        __half2 h0 = u2h(w0[k]);
        ev[2 * k] = __low2float(h0);
        ev[2 * k + 1] = __high2float(h0);
        se = fmaf(ev[2 * k], ev[2 * k], se);
        se = fmaf(ev[2 * k + 1], ev[2 * k + 1], se);
      }
      se += __shfl_xor(se, 1);
      se += __shfl_xor(se, 2);
      se += __shfl_xor(se, 4);
      se += __shfl_xor(se, 8);
      float i0 = scl / fmaxf(sqrtf(se), 1e-12f);
      float i1 = scl / fmaxf(nrm01[r], 1e-12f);
      float i2 = scl / fmaxf(nrm01[N + r], 1e-12f);
      float i3 = scl / fmaxf(sqrtf(np), 1e-12f);
      uint4 a1 = *(const uint4*)&x1b[pb];
      uint4 a2 = *(const uint4*)&x2b[pb];
      unsigned w1[4] = {a1.x, a1.y, a1.z, a1.w};
      unsigned w2[4] = {a2.x, a2.y, a2.z, a2.w};
      unsigned w3[4] = {yy.x, yy.y, yy.z, yy.w};
      float o[8];
#pragma unroll
      for (int k = 0; k < 4; ++k) {
        __half2 h1 = u2h(w1[k]), h2v = u2h(w2[k]), h3 = u2h(w3[k]);
        o[2 * k]     = i0 * ev[2 * k]     + i1 * __low2float(h1)  + i2 * __low2float(h2v)  + i3 * __low2float(h3);
        o[2 * k + 1] = i0 * ev[2 * k + 1] + i1 * __high2float(h1) + i2 * __high2float(h2v) + i3 * __high2float(h3);
      }
      *(float4*)&outp[pb]     = make_float4(o[0], o[1], o[2], o[3]);
      *(float4*)&outp[pb + 4] = make_float4(o[4], o[5], o[6], o[7]);
    }
  }
}

// ---------------- launch ----------------
extern "C" void kernel_launch(void* const* d_in, const int* in_sizes, int n_in,
                              void* d_out, int out_size, void* d_ws, size_t ws_size,
                              hipStream_t stream) {
  const int* rows = (const int*)d_in[0];
  const int* cols = (const int*)d_in[1];
  const float* vals = (const float*)d_in[2];
  const float* emb = (const float*)d_in[3];
  const float* W = (const float*)d_in[4];
  float* out = (float*)d_out;

  int E = in_sizes[0];
  int N = in_sizes[3] / D;
  int L = in_sizes[4] / (D * D);
  float scl = 1.0f / (float)(L + 1);

  int bshift = 10;
  int NBUCK = (N + (1 << bshift) - 1) >> bshift;

  int per = 4096;
  while ((E + per - 1) / per > 512) per *= 2;
  int NW = (E + per - 1) / per;

  char* ws = (char*)d_ws;
  size_t off = 0;
  auto take = [&](size_t bytes) -> void* {
    void* p = ws + off;
    off += (bytes + 255) & ~(size_t)255;
    return p;
  };
  unsigned short* xb0 = (unsigned short*)take((size_t)N * D * 2);   // fp16 emb
  unsigned short* xb1 = (unsigned short*)take((size_t)N * D * 2);
  unsigned short* xb2 = (unsigned short*)take((size_t)N * D * 2);
  unsigned short* wb  = (unsigned short*)take((size_t)L * D * D * 2);
  float* nrm = (float*)take((size_t)2 * N * sizeof(float));
  int* offsets = (int*)take((size_t)(N + 1) * 4);
  int* wghist = (int*)take((size_t)NBUCK_MAX * NW * 4);
  int* wgstart = (int*)take((size_t)NBUCK_MAX * NW * 4);
  int* btot = (int*)take((size_t)NBUCK_MAX * 4);
  uint2* ep = (uint2*)take((size_t)(E + 32) * 8);
  // gbin aliases xb1: consumed (debin2) strictly before spgemm layer 0 writes xb1 (stream-ordered)
  uint2* gbin = (uint2*)xb1;

  // fused: bucket histogram (blocks [0,NW)) + fp16 conversions (remaining blocks)
  int n8x = N * D / 8;
  int n8w = L * D * D / 8;
  int n8tot = n8x + n8w;
  int convb = (n8tot + 255) / 256;
  hist_conv<<<NW + convb, 256, 0, stream>>>(rows, wghist, E, NW, per, bshift,
                                            emb, xb0, W, wb, n8x, n8tot);
  scan_wg<<<NBUCK, 512, 0, stream>>>(wghist, wgstart, btot, NW);
  partition_kernel<<<NW, 256, 0, stream>>>(rows, cols, vals, wgstart, btot, gbin, E, NW, per, bshift);
  debin2<<<NBUCK, 256, 0, stream>>>(gbin, btot, offsets, ep, N, E, bshift, NBUCK);

  int nb64 = (N + 63) / 64;
  // layer 0: gather xb0 -> x1
  spgemm_kernel<0><<<nb64, 512, 0, stream>>>((const char*)xb0, wb, offsets, ep,
                                             xb1, nrm, nullptr, nullptr, nullptr, nullptr, nullptr, N, scl);
  // layer 1: gather xb1 -> x2
  spgemm_kernel<0><<<nb64, 512, 0, stream>>>((const char*)xb1, wb + (size_t)D * D, offsets, ep,
                                             xb2, nrm + N, nullptr, nullptr, nullptr, nullptr, nullptr, N, scl);
  // layer 2: gather xb2, fused final combine -> out
  spgemm_kernel<1><<<nb64, 512, 0, stream>>>((const char*)xb2, wb + (size_t)2 * D * D, offsets, ep,
                                             nullptr, nullptr, xb0, xb1, xb2, nrm, out, N, scl);
}